// Round 11
// baseline (132.009 us; speedup 1.0000x reference)
//
#include <hip/hip_runtime.h>
#include <hip/hip_bf16.h>
#include <stdint.h>

#define N    8192
#define D    256
#define NCLS 100

static constexpr float TEMP    = 0.5f;
static constexpr float SCALE_F = 1.69864360f;  // sqrt(log2e/TEMP)
static constexpr float LN2     = 0.69314718055994531f;

// Partial slots (R11, 256-row bands, 32 bands):
//   row-side, block (x,y=band), wave col-group wc -> slot 4x+wc (0..127)
//   col-side, block (x=band,y<x), wave row-group wr -> slot 128+4y+wr
//   col-side of diagonal block (t,t), row-group wr -> slot 256+wr
#define NSLOT 260

typedef float f32x4 __attribute__((ext_vector_type(4)));
typedef long  lx2  __attribute__((ext_vector_type(2)));

__device__ __forceinline__ unsigned short f2bf(float f) {
  union { float f; unsigned int u; } x; x.f = f;
  unsigned int r = x.u + 0x7fffu + ((x.u >> 16) & 1u);
  return (unsigned short)(r >> 16);
}
__device__ __forceinline__ float bf2f(unsigned short b) {
  union { unsigned int u; float f; } x; x.u = ((unsigned int)b) << 16;
  return x.f;
}
__device__ __forceinline__ void gld16(const void* g, void* l) {
  __builtin_amdgcn_global_load_lds(
      (const __attribute__((address_space(1))) unsigned int*)g,
      (__attribute__((address_space(3))) unsigned int*)l, 16, 0, 0);
}

// fp8 fragment-PAIR-major layout: for row r, k:
//   kq = k>>6, kl = k&63, kkl = kl>>5, q = (kl>>3)&3
//   addr = (r>>4)*4096 + kq*1024 + q*256 + (r&15)*16 + kkl*8 + (k&7)
// -> lane (quad,l15)'s fragments for BOTH kkl halves of one kq are one
//    contiguous 16B (ds_read_b128); staging is contiguous 1024B segments.

// ---- Kernel A: row-normalize; bf16 row-major copy (class sums) + fp8 e4m3
// fragment-pair-major copy (GEMM); zero-fills the partial buffer.
__global__ __launch_bounds__(256) void normalize_kernel(
    const float* __restrict__ emb, const long long* __restrict__ label,
    unsigned short* __restrict__ abf, unsigned char* __restrict__ a8,
    float* __restrict__ part, int* __restrict__ cnt, int* __restrict__ list) {
  const int row  = blockIdx.x * 4 + (threadIdx.x >> 6);
  const int lane = threadIdx.x & 63;
  const float4 v = ((const float4*)(emb + (size_t)row * D))[lane];
  float ss = v.x * v.x + v.y * v.y + v.z * v.z + v.w * v.w;
#pragma unroll
  for (int off = 1; off < 64; off <<= 1) ss += __shfl_xor(ss, off);
  const float s = rsqrtf(ss) * SCALE_F;
  const float x = v.x * s, y = v.y * s, z = v.z * s, wv = v.w * s;

  ushort4 o;
  o.x = f2bf(x); o.y = f2bf(y); o.z = f2bf(z); o.w = f2bf(wv);
  ((ushort4*)(abf + (size_t)row * D))[lane] = o;

  int p = __builtin_amdgcn_cvt_pk_fp8_f32(x, y, 0, false);
  p = __builtin_amdgcn_cvt_pk_fp8_f32(z, wv, p, true);
  // k0 = lane*4: kq=lane>>4, q=(lane>>1)&3, kkl=(lane>>3)&1, k&7=(lane&1)*4
  *(int*)(a8 + (size_t)(row >> 4) * 4096 + (lane >> 4) * 1024 +
          ((lane >> 1) & 3) * 256 + (row & 15) * 16 + ((lane >> 3) & 1) * 8 +
          (lane & 1) * 4) = p;

  // Zero-fill part: 32*260*256 = 2,129,920 floats over 524,288 threads.
  const int gtid = blockIdx.x * 256 + threadIdx.x;
#pragma unroll
  for (int k = 0; k < 5; ++k) {
    const size_t idx = (size_t)k * 524288 + gtid;
    if (idx < (size_t)32 * NSLOT * 256) part[idx] = 0.f;
  }

  if (lane == 0) {
    const int c = (int)label[row];
    const int slot = atomicAdd(cnt + c, 1);
    list[c * 256 + slot] = row;
  }
}

struct TileCoord { int x, y; };
__device__ __forceinline__ TileCoord tri_decode(int b) {
  int x = (int)((-1.0f + sqrtf(1.0f + 8.0f * (float)b)) * 0.5f);
  while ((x + 1) * (x + 2) / 2 <= b) ++x;
  while (x * (x + 1) / 2 > b) --x;
  return {x, b - x * (x + 1) / 2};
}

// ---- Kernel B: symmetric (strict upper triangle), one block per live
// 256x256 sub-tile: 32*33/2 = 528 blocks, 1024 threads (16 waves, each
// owning a 64x64 output region), 128 KB LDS, 1 block/CU, 4 waves/SIMD.
//
// R11 theory (L2 same-address contention): R7's ablation showed
// stage-only == stage+compute+epilogue (~24.6 us/rep) -> the L2->CU load
// path is the wall at ~9 B/cyc/CU, 4-16x below the distinct-address L2
// ceiling. Cause: all blocks in a tile-column stage the IDENTICAL panel
// near-synchronized -> L2 banks serialize same-line responses. Fixes:
// (1) 256^2 tiles halve total line-requests and sharing multiplicity;
// (2) block-id-skewed segment order de-camps the banks;
// (3) 2-phase K-split staging overlaps the second 64 KB with MFMA work.
__global__ __launch_bounds__(1024, 4) void simexp_rowsum_kernel(
    const unsigned char* __restrict__ A, float* __restrict__ part) {
  __shared__ __align__(16) unsigned char sa[16 * 4096];  // 64 KB A tile
  __shared__ __align__(16) unsigned char sb[16 * 4096];  // 64 KB B tile
  const int tid  = threadIdx.x;
  const int w    = tid >> 6;   // 0..15
  const int lane = tid & 63;
  const int quad = lane >> 4;
  const int l15  = lane & 15;
  const int wr   = w & 3;      // wave row-group (64 rows)
  const int wc   = w >> 2;     // wave col-group (64 cols)

  const TileCoord tc = tri_decode(blockIdx.x);
  const int x = tc.x, y = tc.y;      // tile col, tile row (y <= x)
  const int pr0 = y << 4;            // first 16-row panel of A tile
  const int pc0 = x << 4;            // first 16-row panel of B tile
  const bool diag = (x == y);
  const bool needmask  = diag && (wc == wr);
  const bool skipstore = diag && (wc < wr);  // region strictly lower

  const int rot = blockIdx.x & 31;   // de-synchronize L2 address streams

  // ---- stage half-K 0 (kq 0..1): 32 segs of 1024B per tile, 2/wave.
#pragma unroll
  for (int p = 0; p < 2; ++p) {
    const int s = (w * 2 + p + rot) & 31;          // A seg (skewed)
    gld16(A + (size_t)(pr0 + (s >> 1)) * 4096 + (s & 1) * 1024 + lane * 16,
          sa + (s >> 1) * 4096 + (s & 1) * 1024);
    const int t = (w * 2 + p + rot + 16) & 31;     // B seg (skewed+offset)
    gld16(A + (size_t)(pc0 + (t >> 1)) * 4096 + (t & 1) * 1024 + lane * 16,
          sb + (t >> 1) * 4096 + (t & 1) * 1024);
  }
  __syncthreads();  // half 0 ready

  // ---- issue half-K 1 (kq 2..3) async; it completes under compute.
#pragma unroll
  for (int p = 0; p < 2; ++p) {
    const int s = (w * 2 + p + rot) & 31;
    gld16(A + (size_t)(pr0 + (s >> 1)) * 4096 + 2048 + (s & 1) * 1024 +
              lane * 16,
          sa + (s >> 1) * 4096 + 2048 + (s & 1) * 1024);
    const int t = (w * 2 + p + rot + 16) & 31;
    gld16(A + (size_t)(pc0 + (t >> 1)) * 4096 + 2048 + (t & 1) * 1024 +
              lane * 16,
          sb + (t >> 1) * 4096 + 2048 + (t & 1) * 1024);
  }

  const int pam = wr * 4;   // wave's A panel base
  const int pbn = wc * 4;   // wave's B panel base
  const int lo  = quad * 256 + l15 * 16;

  f32x4 acc[4][4];
#pragma unroll
  for (int mt = 0; mt < 4; ++mt)
#pragma unroll
    for (int nt = 0; nt < 4; ++nt) acc[mt][nt] = (f32x4){0.f, 0.f, 0.f, 0.f};

  // ---- compute half 0 (kq 0,1) while half 1 streams in.
#pragma unroll
  for (int kq = 0; kq < 2; ++kq) {
    lx2 aF[4], bF[4];
#pragma unroll
    for (int mt = 0; mt < 4; ++mt)
      aF[mt] = *(const lx2*)(sa + (pam + mt) * 4096 + kq * 1024 + lo);
#pragma unroll
    for (int nt = 0; nt < 4; ++nt)
      bF[nt] = *(const lx2*)(sb + (pbn + nt) * 4096 + kq * 1024 + lo);
#pragma unroll
    for (int kkl = 0; kkl < 2; ++kkl)
#pragma unroll
      for (int mt = 0; mt < 4; ++mt)
#pragma unroll
        for (int nt = 0; nt < 4; ++nt)
          acc[mt][nt] = __builtin_amdgcn_mfma_f32_16x16x32_fp8_fp8(
              aF[mt][kkl], bF[nt][kkl], acc[mt][nt], 0, 0, 0);
  }
  __syncthreads();  // drains half-1 loads

  // ---- compute half 1 (kq 2,3).
#pragma unroll
  for (int kq = 2; kq < 4; ++kq) {
    lx2 aF[4], bF[4];
#pragma unroll
    for (int mt = 0; mt < 4; ++mt)
      aF[mt] = *(const lx2*)(sa + (pam + mt) * 4096 + kq * 1024 + lo);
#pragma unroll
    for (int nt = 0; nt < 4; ++nt)
      bF[nt] = *(const lx2*)(sb + (pbn + nt) * 4096 + kq * 1024 + lo);
#pragma unroll
    for (int kkl = 0; kkl < 2; ++kkl)
#pragma unroll
      for (int mt = 0; mt < 4; ++mt)
#pragma unroll
        for (int nt = 0; nt < 4; ++nt)
          acc[mt][nt] = __builtin_amdgcn_mfma_f32_16x16x32_fp8_fp8(
              aF[mt][kkl], bF[nt][kkl], acc[mt][nt], 0, 0, 0);
  }

  // ---- epilogue: exp2, diagonal mask, row + column partials.
  float rowpart[4][4];
  float colpart[4] = {0.f, 0.f, 0.f, 0.f};
#pragma unroll
  for (int mt = 0; mt < 4; ++mt)
#pragma unroll
    for (int e = 0; e < 4; ++e) rowpart[mt][e] = 0.f;
#pragma unroll
  for (int mt = 0; mt < 4; ++mt)
#pragma unroll
    for (int nt = 0; nt < 4; ++nt)
#pragma unroll
      for (int e = 0; e < 4; ++e) {
        float v = __builtin_amdgcn_exp2f(acc[mt][nt][e]);
        if (needmask) {
          const int iw = mt * 16 + quad * 4 + e;  // row within 64x64 region
          const int jw = nt * 16 + l15;           // col within 64x64 region
          v = (iw < jw) ? v : 0.f;
        }
        rowpart[mt][e] += v;
        colpart[nt] += v;
      }

  if (!skipstore) {
    float* rowdst =
        part + ((size_t)y * NSLOT + 4 * x + wc) * 256 + wr * 64;
    float* coldst =
        part + ((size_t)x * NSLOT + (diag ? (256 + wr) : (128 + 4 * y + wr))) *
                   256 + wc * 64;

    // Column reduce over the wave's 64 rows (lane bits 4,5).
#pragma unroll
    for (int nt = 0; nt < 4; ++nt) {
      float v = colpart[nt];
      v += __shfl_xor(v, 16);
      v += __shfl_xor(v, 32);
      if (quad == 0) coldst[nt * 16 + l15] = v;
    }
    // Row reduce over the wave's 64 cols (lane bits 0..3).
#pragma unroll
    for (int mt = 0; mt < 4; ++mt)
#pragma unroll
      for (int e = 0; e < 4; ++e) {
        float v = rowpart[mt][e];
        v += __shfl_xor(v, 1);
        v += __shfl_xor(v, 2);
        v += __shfl_xor(v, 4);
        v += __shfl_xor(v, 8);
        if (l15 == 0) rowdst[mt * 16 + quad * 4 + e] = v;
      }
  }
}

__global__ __launch_bounds__(256) void finalize_kernel(
    const unsigned short* __restrict__ abf, const float* __restrict__ part,
    const long long* __restrict__ label, const int* __restrict__ cnt,
    const int* __restrict__ list, float* __restrict__ out) {
  __shared__ float red[4];
  __shared__ int rows_l[256];
  const int tid  = threadIdx.x;
  const int w    = tid >> 6;
  const int lane = tid & 63;

  if (blockIdx.x < NCLS) {
    const int c = blockIdx.x;
    const int m = cnt[c];
    if (m <= 1) return;
    if (tid < m) rows_l[tid] = list[c * 256 + tid];
    __syncthreads();
    float acc = 0.f;
    for (int s = 0; s < m; ++s)
      acc += bf2f(abf[(size_t)rows_l[s] * D + tid]);
    float v = acc * acc;
#pragma unroll
    for (int off = 1; off < 64; off <<= 1) v += __shfl_xor(v, off);
    if (lane == 0) red[w] = v;
    __syncthreads();
    if (tid == 0) {
      const float ssq = red[0] + red[1] + red[2] + red[3];
      const float term = (ssq * LN2 - 2.0f * (float)m) / (float)(m - 1);
      atomicAdd(out, -term);
    }
  } else {
    // rowsum_i = sum of the 260 per-block partials for this row's band.
    const int i = (blockIdx.x - NCLS) * 256 + tid;
    const int band = i >> 8, r = i & 255;
    const float* ps = part + (size_t)band * NSLOT * 256 + r;
    float rs = 0.f;
#pragma unroll 13
    for (int s = 0; s < NSLOT; ++s) rs += ps[(size_t)s * 256];
    const int c = (int)label[i];
    float v = 0.f;
    if (cnt[c] > 1)
      v = __builtin_amdgcn_logf(rs) * LN2;
#pragma unroll
    for (int off = 1; off < 64; off <<= 1) v += __shfl_xor(v, off);
    if (lane == 0) red[w] = v;
    __syncthreads();
    if (tid == 0)
      atomicAdd(out, red[0] + red[1] + red[2] + red[3]);
  }
}

extern "C" void kernel_launch(void* const* d_in, const int* in_sizes, int n_in,
                              void* d_out, int out_size, void* d_ws,
                              size_t ws_size, hipStream_t stream) {
  const float* emb = (const float*)d_in[0];
  const long long* label = (const long long*)d_in[1];
  float* out = (float*)d_out;

  char* ws = (char*)d_ws;
  unsigned short* abf = (unsigned short*)ws;            // 4 MB bf16 row-major
  unsigned char* a8 = (unsigned char*)(ws + (size_t)N * D * 2);  // 2 MB fp8
  float* part = (float*)(ws + (size_t)N * D * 3);       // 32*260*256 f32
  int* cnt = (int*)(ws + (size_t)N * D * 3 + (size_t)32 * NSLOT * 256 * 4);
  int* list = cnt + 128;                                // NCLS*256 ints

  hipMemsetAsync(cnt, 0, 128 * 4, stream);
  hipMemsetAsync(out, 0, sizeof(float), stream);

  normalize_kernel<<<N / 4, 256, 0, stream>>>(emb, label, abf, a8, part, cnt,
                                              list);

  // One block per live upper-triangle 256x256 sub-tile: 32*33/2 = 528.
  simexp_rowsum_kernel<<<528, 1024, 0, stream>>>(a8, part);

  finalize_kernel<<<NCLS + N / 256, 256, 0, stream>>>(abf, part, label, cnt,
                                                      list, out);
}